// Round 4
// baseline (235.510 us; speedup 1.0000x reference)
//
#include <hip/hip_runtime.h>

// R4: attn computes S^T via swapped MFMA operands -> per-lane owns 1 q-row x
// 4 consecutive k-cols => float4 dep/out, int4 mask, scalar softmax chain +
// 2 shuffles. proj rewritten as 4-wave 128x128 LDS-tiled GEMM (BK=64,
// stride-72 padding). prep unchanged (convert X + transpose W).

typedef _Float16 f16;
typedef _Float16 f16x4 __attribute__((ext_vector_type(4)));
typedef _Float16 f16x8 __attribute__((ext_vector_type(8)));
typedef float    f32x4 __attribute__((ext_vector_type(4)));

#define NTOK   512
#define DMODEL 768
#define BATCH  8
#define NHEAD  12
#define NEGV   (-1e9f)
#define KPAD   72   // LDS row stride in halfs (144 B): 16B-aligned, 2-way banks

// ---------------------------------------------------------------------------
// prep: blocks [0,3072) convert X fp32->f16; blocks [3072,4224) transpose
// Wq/Wk 32x32 tiles -> Wt[n][k] f16 (rows 0-767 Wq^T, 768-1535 Wk^T).
__global__ __launch_bounds__(256)
void prep_kernel(const float* __restrict__ X, f16* __restrict__ Xh,
                 const float* __restrict__ Wq, const float* __restrict__ Wk,
                 f16* __restrict__ Wt) {
    const int bx = blockIdx.x;
    if (bx < 3072) {
        const size_t i = ((size_t)bx * 256 + threadIdx.x) * 4;
        float4 v = *(const float4*)&X[i];
        f16x4 h = { (f16)v.x, (f16)v.y, (f16)v.z, (f16)v.w };
        *(f16x4*)&Xh[i] = h;
    } else {
        __shared__ float tile[32][33];
        const int id = bx - 3072;
        const int kb = (id % 24) * 32;
        const int nb = (id / 24) * 32;          // combined n in [0,1536)
        const float* __restrict__ W = (nb < 768) ? Wq : Wk;
        const int nc = (nb < 768) ? nb : nb - 768;
        const int tx = threadIdx.x & 31, ty = threadIdx.x >> 5;
        #pragma unroll
        for (int i = 0; i < 4; ++i)
            tile[ty + i*8][tx] = W[(size_t)(kb + ty + i*8) * DMODEL + nc + tx];
        __syncthreads();
        #pragma unroll
        for (int i = 0; i < 4; ++i)
            Wt[(size_t)(nb + ty + i*8) * DMODEL + kb + tx] = (f16)tile[tx][ty + i*8];
    }
}

// ---------------------------------------------------------------------------
// proj: 128x128 tile per block, 4 waves in 2x2 quadrants, BK=64 LDS-staged.
// QK[4096][1536] = Xh * Wt^T + bias. grid (32, 12), block 256.
__global__ __launch_bounds__(256)
void proj_mfma(const f16* __restrict__ Xh, const f16* __restrict__ Wt,
               const float* __restrict__ bq, const float* __restrict__ bk,
               f16* __restrict__ QK) {
    const int m0 = blockIdx.x * 128;
    const int n0 = blockIdx.y * 128;
    const int tid = threadIdx.x;
    const int wid = tid >> 6, l = tid & 63;
    const int l15 = l & 15, quad = l >> 4;
    const int wm = (wid & 1) * 64;   // wave row quadrant
    const int wn = (wid >> 1) * 64;  // wave col quadrant

    __shared__ f16 As[128 * KPAD];   // 18 KB
    __shared__ f16 Bs[128 * KPAD];   // 18 KB

    f32x4 acc[4][4];
    #pragma unroll
    for (int i = 0; i < 4; ++i)
        #pragma unroll
        for (int j = 0; j < 4; ++j) acc[i][j] = (f32x4){0.f, 0.f, 0.f, 0.f};

    // staging map: thread -> row tid>>1, 32-half (64B) chunk (tid&1)*32
    const int srow  = tid >> 1;
    const int scol  = (tid & 1) * 32;

    for (int kt = 0; kt < DMODEL; kt += 64) {
        const f16* __restrict__ Asrc = Xh + (size_t)(m0 + srow) * DMODEL + kt + scol;
        const f16* __restrict__ Bsrc = Wt + (size_t)(n0 + srow) * DMODEL + kt + scol;
        #pragma unroll
        for (int j = 0; j < 4; ++j) {
            f16x8 av = *(const f16x8*)(Asrc + j * 8);
            *(f16x8*)&As[srow * KPAD + scol + j * 8] = av;
        }
        #pragma unroll
        for (int j = 0; j < 4; ++j) {
            f16x8 bv = *(const f16x8*)(Bsrc + j * 8);
            *(f16x8*)&Bs[srow * KPAD + scol + j * 8] = bv;
        }
        __syncthreads();
        #pragma unroll
        for (int ks = 0; ks < 2; ++ks) {
            f16x8 a[4], b[4];
            #pragma unroll
            for (int mi = 0; mi < 4; ++mi)
                a[mi] = *(f16x8*)&As[(wm + mi*16 + l15) * KPAD + ks*32 + quad*8];
            #pragma unroll
            for (int ni = 0; ni < 4; ++ni)
                b[ni] = *(f16x8*)&Bs[(wn + ni*16 + l15) * KPAD + ks*32 + quad*8];
            #pragma unroll
            for (int mi = 0; mi < 4; ++mi)
                #pragma unroll
                for (int ni = 0; ni < 4; ++ni)
                    acc[mi][ni] = __builtin_amdgcn_mfma_f32_16x16x32_f16(
                        a[mi], b[ni], acc[mi][ni], 0, 0, 0);
        }
        __syncthreads();
    }

    #pragma unroll
    for (int ni = 0; ni < 4; ++ni) {
        const int col = n0 + wn + ni * 16 + l15;
        const float bv = (col < 768) ? bq[col] : bk[col - 768];
        #pragma unroll
        for (int mi = 0; mi < 4; ++mi)
            #pragma unroll
            for (int r = 0; r < 4; ++r) {
                const int row = m0 + wm + mi * 16 + quad * 4 + r;
                QK[(size_t)row * 1536 + col] = (f16)(acc[mi][ni][r] + bv);
            }
    }
}

// ---------------------------------------------------------------------------
// attn: block = 4 waves = 64 q rows of one (b,h); K-head in LDS.
// S^T orientation: A = K-fragment (m = k-token), B = Q-fragment (n = q-row).
// Lane owns q-row l15, k-cols t*16 + quad*4 + {0..3}. grid (8,12,8), block 256.
__global__ __launch_bounds__(256, 2)
void attn_mfma(const f16* __restrict__ QK, const float* __restrict__ dep,
               const int* __restrict__ mask, float* __restrict__ out) {
    const int qt = blockIdx.x, h = blockIdx.y, b = blockIdx.z;
    const int tid = threadIdx.x;
    const int wid = tid >> 6, l = tid & 63;
    const int l15 = l & 15, quad = l >> 4;
    const int qrow = qt * 64 + wid * 16 + l15;   // this lane's q row

    __shared__ f16 Ks[NTOK * KPAD];   // 72 KB

    // stage K-head: 512 tokens x 8 chunks of f16x8
    {
        const f16* __restrict__ Ksrc = QK + (size_t)b * NTOK * 1536 + 768 + h * 64;
        #pragma unroll
        for (int c = 0; c < 16; ++c) {
            const int chunk = tid + c * 256;
            const int token = chunk >> 3;
            const int part  = chunk & 7;
            f16x8 v = *(const f16x8*)(Ksrc + (size_t)token * 1536 + part * 8);
            *(f16x8*)&Ks[token * KPAD + part * 8] = v;
        }
    }
    __syncthreads();

    f32x4 acc[32];
    #pragma unroll
    for (int t = 0; t < 32; ++t) acc[t] = (f32x4){0.f, 0.f, 0.f, 0.f};

    const f16* __restrict__ Qb = QK + (size_t)(b * NTOK + qrow) * 1536 + h * 64 + quad * 8;
    const f16x8 qf0 = *(const f16x8*)(Qb);
    const f16x8 qf1 = *(const f16x8*)(Qb + 32);

    #pragma unroll
    for (int t = 0; t < 32; ++t) {
        f16x8 k0 = *(f16x8*)&Ks[(t * 16 + l15) * KPAD + quad * 8];
        acc[t] = __builtin_amdgcn_mfma_f32_16x16x32_f16(k0, qf0, acc[t], 0, 0, 0);
        f16x8 k1 = *(f16x8*)&Ks[(t * 16 + l15) * KPAD + 32 + quad * 8];
        acc[t] = __builtin_amdgcn_mfma_f32_16x16x32_f16(k1, qf1, acc[t], 0, 0, 0);
    }

    // blend + mask: lane's cols are 4 consecutive -> float4/int4
    const float SC = (1.0f - 0.1f) / 8.0f;   // (1-d_weight)/sqrt(dk)
    const float DW = 0.1f;
    const float* __restrict__ deprow = dep + ((size_t)b * NTOK + qrow) * NTOK;
    const int*   __restrict__ mrow   = mask + b * NTOK;
    #pragma unroll
    for (int t = 0; t < 32; ++t) {
        const int c0 = t * 16 + quad * 4;
        const int4   mv = *(const int4*)  &mrow[c0];
        const float4 dv = *(const float4*)&deprow[c0];
        acc[t][0] = mv.x ? SC * acc[t][0] + DW * dv.x : NEGV;
        acc[t][1] = mv.y ? SC * acc[t][1] + DW * dv.y : NEGV;
        acc[t][2] = mv.z ? SC * acc[t][2] + DW * dv.z : NEGV;
        acc[t][3] = mv.w ? SC * acc[t][3] + DW * dv.w : NEGV;
    }

    // softmax over the lane's 128 values + cross-quad (same l15) reduction
    float m = NEGV;
    #pragma unroll
    for (int t = 0; t < 32; ++t)
        #pragma unroll
        for (int r = 0; r < 4; ++r) m = fmaxf(m, acc[t][r]);
    m = fmaxf(m, __shfl_xor(m, 16));
    m = fmaxf(m, __shfl_xor(m, 32));

    float s = 0.f;
    #pragma unroll
    for (int t = 0; t < 32; ++t)
        #pragma unroll
        for (int r = 0; r < 4; ++r) {
            const float e = __expf(acc[t][r] - m);
            acc[t][r] = e;
            s += e;
        }
    s += __shfl_xor(s, 16);
    s += __shfl_xor(s, 32);
    const float inv = 1.0f / s;

    float* __restrict__ orow = out + ((size_t)((b * NHEAD + h) * NTOK) + qrow) * NTOK;
    #pragma unroll
    for (int t = 0; t < 32; ++t) {
        float4 p = { acc[t][0] * inv, acc[t][1] * inv, acc[t][2] * inv, acc[t][3] * inv };
        *(float4*)&orow[t * 16 + quad * 4] = p;
    }
}

// ---------------------------------------------------------------------------
extern "C" void kernel_launch(void* const* d_in, const int* in_sizes, int n_in,
                              void* d_out, int out_size, void* d_ws, size_t ws_size,
                              hipStream_t stream) {
    const float* X    = (const float*)d_in[0];
    const int*   mask = (const int*)  d_in[1];
    const float* dep  = (const float*)d_in[2];
    const float* Wq   = (const float*)d_in[3];
    const float* bq   = (const float*)d_in[4];
    const float* Wk   = (const float*)d_in[5];
    const float* bk   = (const float*)d_in[6];
    float* out = (float*)d_out;

    f16* Xh = (f16*)d_ws;                                  // 4096*768
    f16* Wt = Xh + (size_t)BATCH * NTOK * DMODEL;          // 1536*768
    f16* QK = Wt + (size_t)1536 * DMODEL;                  // 4096*1536

    prep_kernel<<<dim3(3072 + 1152), 256, 0, stream>>>(X, Xh, Wq, Wk, Wt);
    proj_mfma<<<dim3(4096 / 128, 1536 / 128), 256, 0, stream>>>(Xh, Wt, bq, bk, QK);
    attn_mfma<<<dim3(NTOK / 64, NHEAD, BATCH), 256, 0, stream>>>(QK, dep, mask, out);
}